// Round 12
// baseline (388.919 us; speedup 1.0000x reference)
//
#include <hip/hip_runtime.h>

typedef unsigned short ushort_t;
typedef unsigned int uint_t;
typedef __attribute__((ext_vector_type(8))) short bf16x8;
typedef __attribute__((ext_vector_type(4))) float f32x4;

#define C_DIM 64
#define P_DIM 1296
#define N_DIM 2000
#define B_DIM 256
#define K_DIM (C_DIM * P_DIM)               // 82944
#define XB_ELEMS (B_DIM * K_DIM)            // 21233664
#define XB_ELEMS_PAD (XB_ELEMS + 256)
#define XB_BYTES ((size_t)XB_ELEMS_PAD * 2) // 42467840
#define SLICES 32
#define OUT_ELEMS (B_DIM * N_DIM)           // 512000

static __device__ __forceinline__ ushort_t f2bf(float f) {
  unsigned u = __builtin_bit_cast(unsigned, f);
  u += 0x7fffu + ((u >> 16) & 1u);
  return (ushort_t)(u >> 16);
}

// ---------------- x (fp32) -> Xb (bf16) with zeroed pad tail ----------------
__global__ void klindt_cvt_kernel(const float4* __restrict__ x,
                                  unsigned long long* __restrict__ xb) {
  int idx = blockIdx.x * 256 + threadIdx.x;
  if (idx >= XB_ELEMS_PAD / 4) return;
  unsigned long long r = 0ull;
  if (idx < XB_ELEMS / 4) {
    float4 v = x[idx];
    r = (unsigned long long)f2bf(v.x) | ((unsigned long long)f2bf(v.y) << 16) |
        ((unsigned long long)f2bf(v.z) << 32) |
        ((unsigned long long)f2bf(v.w) << 48);
  }
  xb[idx] = r;
}

// ---------------- main GEMM: partials[slice][b][n] ----------------
// H13: ZERO barriers. Each wave is an independent pipeline owning a
// 128m x 32n output slab: A staged into WAVE-PRIVATE LDS (16 KB:
// [128 m][64 k] bf16, 8x16B slots/row XOR-swizzled by m&7) via
// global_load_lds from the XCD-L2-pinned xb — same-wave program order +
// counted vmcnt replaces __syncthreads. B (mw) register-direct with 1-step
// prefetch (static bank parity). 8 independent wave-streams/CU keep the HBM
// queue full; evidence: R8 reps were duration-invariant to HBM-vs-L3
// sourcing => prior structure was sync/chain-bound, not memory-bound.
// Grid 1024 = 8 XCD x 4 slices x 2 m-halves x 16 n-groups (waves: x4 nw).
__global__ void __launch_bounds__(256, 2) klindt_gemm_kernel(
    const char* __restrict__ xbb, const char* __restrict__ mwb,
    const float* __restrict__ rw, float* __restrict__ partials) {
  __shared__ ushort_t sA[4][8192];  // 4 waves x 16 KB, wave-private

  const int tid = threadIdx.x;
  const int lane = tid & 63;
  const int wid = tid >> 6;  // 0..3
  const int r15 = lane & 15, g4 = lane >> 4;
  const int bid = blockIdx.x;
  const int slice = (bid & 7) + 8 * ((bid >> 3) & 3);  // XCD-pinned
  const int r5 = bid >> 5;                             // 0..31
  const int m0 = (r5 & 1) * 128;
  const int nb = ((r5 >> 1) * 4 + wid) * 32;           // n-window 0..63
  const int c0 = slice * 2;

  ushort_t* myA = sA[wid];

  f32x4 acc[8][2];
#pragma unroll
  for (int i = 0; i < 8; ++i)
#pragma unroll
    for (int j = 0; j < 2; ++j) {
      acc[i][j][0] = 0.f; acc[i][j][1] = 0.f;
      acc[i][j][2] = 0.f; acc[i][j][3] = 0.f;
    }

  // ---- A staging constants (rule #21: linear LDS dest via implicit
  //      lane*16, inverse-swizzled per-lane global src) ----
  // cell = i*64+lane -> row = i*8+(lane>>3), slot = lane&7,
  // src k-slot = slot ^ (row&7) = (lane&7) ^ ((lane>>3)&7)  (i*8 = 0 mod 8)
  const int ss8 = (((lane & 7) ^ ((lane >> 3) & 7))) * 8;  // k elems
  const uint_t a_srcm = (uint_t)(m0 + (lane >> 3)) * (uint_t)K_DIM * 2u;

  // ---- B constants: lane&15 = n within frag, g4 = k-group ----
  const int nA = nb + r15, nB = nb + 16 + r15;
  const bool okA = nA < N_DIM, okB = nB < N_DIM;
  const uint_t nAb = (uint_t)(okA ? nA : N_DIM - 1) * 4u;
  const uint_t nBb = (uint_t)(okB ? nB : N_DIM - 1) * 4u;
  const float rv0l = okA ? rw[c0 * N_DIM + nA] : 0.f;
  const float rv1l = okB ? rw[c0 * N_DIM + nB] : 0.f;
  const float rv0h = okA ? rw[(c0 + 1) * N_DIM + nA] : 0.f;
  const float rv1h = okB ? rw[(c0 + 1) * N_DIM + nB] : 0.f;
  const uint_t pg = (uint_t)(g4 * 8);

  // ---- A fragment read offsets (bytes), swizzle-consistent, per KH ----
  const int aoff0 = r15 * 128 + ((g4 ^ (r15 & 7)) & 7) * 16;
  const int aoff1 = r15 * 128 + (((g4 + 4) ^ (r15 & 7)) & 7) * 16;

  float mvE[16], mvO[16];  // B prefetch double-bank (static parity)
  bf16x8 bf0, bf1;

  // Stage k-window [P0, P0+64) of channel C into myA (16 x gl_lds).
#define STAGE(C, P0)                                                          \
  do {                                                                        \
    uint_t kl_ = (uint_t)(P0) + (uint_t)ss8;                                  \
    if (kl_ > 1288u) kl_ = 1288u; /* tail dup; killed by B=0 */               \
    uint_t ko_ = ((uint_t)(C) * (uint_t)P_DIM + kl_) * 2u;                    \
    const char* s_ = xbb + (a_srcm + ko_);                                    \
    _Pragma("unroll") for (int i_ = 0; i_ < 16; ++i_)                         \
        __builtin_amdgcn_global_load_lds(                                     \
            (const __attribute__((address_space(1))) unsigned int*)           \
                (s_ + i_ * 1327104),                                          \
            (__attribute__((address_space(3))) unsigned int*)(&myA[i_ * 512]),\
            16, 0, 0);                                                        \
  } while (0)

#define ISSUE_B(MV, C_, SP_)                                                  \
  do {                                                                        \
    uint_t ps_ = (uint_t)((SP_)*32) + pg;                                     \
    if (ps_ > 1288u) ps_ = 1288u;                                             \
    const char* base_ = mwb + (ps_ * 512000u + (uint_t)(C_)*8000u);           \
    _Pragma("unroll") for (int j_ = 0; j_ < 8; ++j_) {                        \
      MV[j_] = *(const float*)(base_ + (uint_t)j_ * 512000u + nAb);           \
      MV[8 + j_] = *(const float*)(base_ + (uint_t)j_ * 512000u + nBb);       \
    }                                                                         \
  } while (0)

#define CVT(MV, RA, RB, TAIL)                                                 \
  do {                                                                        \
    float ra_ = (RA), rb_ = (RB);                                             \
    if ((TAIL) && g4 >= 2) { ra_ = 0.f; rb_ = 0.f; }                          \
    _Pragma("unroll") for (int j_ = 0; j_ < 8; ++j_) {                        \
      bf0[j_] = (short)f2bf(MV[j_] * ra_);                                    \
      bf1[j_] = (short)f2bf(MV[8 + j_] * rb_);                                \
    }                                                                         \
  } while (0)

#define MFMA_STEP(AOFF)                                                       \
  do {                                                                        \
    __builtin_amdgcn_s_setprio(1);                                            \
    _Pragma("unroll") for (int fm_ = 0; fm_ < 8; ++fm_) {                     \
      bf16x8 a_ = *(const bf16x8*)((const char*)myA + ((AOFF) + fm_ * 2048)); \
      acc[fm_][0] =                                                           \
          __builtin_amdgcn_mfma_f32_16x16x32_bf16(a_, bf0, acc[fm_][0], 0,0,0);\
      acc[fm_][1] =                                                           \
          __builtin_amdgcn_mfma_f32_16x16x32_bf16(a_, bf1, acc[fm_][1], 0,0,0);\
    }                                                                         \
    __builtin_amdgcn_s_setprio(0);                                            \
  } while (0)

  // lgkm guard: prior ds_reads retired before gl_lds overwrites the buffer
#define GUARD                                                                 \
  asm volatile("s_waitcnt lgkmcnt(0)" ::: "memory");                          \
  __builtin_amdgcn_sched_barrier(0)
  // drain the 16 stage loads (oldest); B prefetch (16 newest) rides
#define VM16                                                                  \
  asm volatile("s_waitcnt vmcnt(16)" ::: "memory");                           \
  __builtin_amdgcn_sched_barrier(0)
#define VM0                                                                   \
  asm volatile("s_waitcnt vmcnt(0)" ::: "memory");                            \
  __builtin_amdgcn_sched_barrier(0)

  // One channel: 20 staged pairs + 1 tail step (sp=40, 16 valid k).
  // MVA = bank holding even-sp steps of this channel.
#define CHANNEL(C, MVA, MVB, RA, RB, LASTCH)                                  \
  do {                                                                        \
    for (int u_ = 0; u_ < 20; ++u_) {                                         \
      GUARD;                                                                  \
      STAGE(C, u_ * 64);                                                      \
      __builtin_amdgcn_sched_barrier(0);                                      \
      ISSUE_B(MVB, C, 2 * u_ + 1);                                            \
      CVT(MVA, RA, RB, false);                                                \
      VM16;                                                                   \
      MFMA_STEP(aoff0);                                                       \
      ISSUE_B(MVA, C, 2 * u_ + 2); /* u=19 -> sp=40 tail prefetch */          \
      CVT(MVB, RA, RB, false);                                                \
      MFMA_STEP(aoff1);                                                       \
    }                                                                         \
    GUARD;                                                                    \
    STAGE(C, 1280);                                                           \
    __builtin_amdgcn_sched_barrier(0);                                        \
    if (!(LASTCH)) { ISSUE_B(MVB, (C) + 1, 0); }                              \
    CVT(MVA, RA, RB, true);                                                   \
    if (LASTCH) { VM0; } else { VM16; }                                       \
    MFMA_STEP(aoff0);                                                         \
  } while (0)

  // ---- prologue: first B bank in flight before channel 0 ----
  ISSUE_B(mvE, c0, 0);
  CHANNEL(c0, mvE, mvO, rv0l, rv1l, false);
  CHANNEL(c0 + 1, mvO, mvE, rv0h, rv1h, true);

  // ---- epilogue: fp32 partials for this K-slice ----
  float* pb = partials + (size_t)slice * OUT_ELEMS;
#pragma unroll
  for (int fm = 0; fm < 8; ++fm) {
    int m = m0 + fm * 16 + g4 * 4;
    if (okA) {
#pragma unroll
      for (int rr = 0; rr < 4; ++rr)
        pb[(m + rr) * N_DIM + nA] = acc[fm][0][rr];
    }
    if (okB) {
#pragma unroll
      for (int rr = 0; rr < 4; ++rr)
        pb[(m + rr) * N_DIM + nB] = acc[fm][1][rr];
    }
  }
#undef CHANNEL
#undef VM0
#undef VM16
#undef GUARD
#undef MFMA_STEP
#undef CVT
#undef ISSUE_B
#undef STAGE
}

// ---------------- deterministic split-K reduction ----------------
__global__ void klindt_reduce_kernel(const float* __restrict__ part,
                                     float* __restrict__ out) {
  int i = blockIdx.x * 256 + threadIdx.x;
  if (i < OUT_ELEMS) {
    float s = 0.f;
#pragma unroll
    for (int k = 0; k < SLICES; ++k) s += part[(size_t)k * OUT_ELEMS + i];
    out[i] = s;
  }
}

extern "C" void kernel_launch(void* const* d_in, const int* in_sizes, int n_in,
                              void* d_out, int out_size, void* d_ws,
                              size_t ws_size, hipStream_t stream) {
  (void)in_sizes; (void)n_in; (void)out_size; (void)ws_size;
  const float* x = (const float*)d_in[0];
  const char* mwb = (const char*)d_in[1];
  const float* rw = (const float*)d_in[2];
  float* out = (float*)d_out;

  char* xbb = (char*)d_ws;
  float* partials = (float*)((char*)d_ws + XB_BYTES);

  {
    int nvec = XB_ELEMS_PAD / 4;
    int grid = (nvec + 255) / 256;
    klindt_cvt_kernel<<<grid, 256, 0, stream>>>((const float4*)x,
                                                (unsigned long long*)xbb);
  }
  {
    klindt_gemm_kernel<<<1024, 256, 0, stream>>>(xbb, mwb, rw, partials);
  }
  {
    int grid = (OUT_ELEMS + 255) / 256;
    klindt_reduce_kernel<<<grid, 256, 0, stream>>>(partials, out);
  }
}

// Round 13
// 225.708 us; speedup vs baseline: 1.7231x; 1.7231x over previous
//
#include <hip/hip_runtime.h>

typedef unsigned short ushort_t;
typedef unsigned int uint_t;
typedef __attribute__((ext_vector_type(8))) short bf16x8;
typedef __attribute__((ext_vector_type(4))) float f32x4;

#define C_DIM 64
#define P_DIM 1296
#define N_DIM 2000
#define B_DIM 256
#define K_DIM (C_DIM * P_DIM)               // 82944
#define XB_ELEMS (B_DIM * K_DIM)            // 21233664
#define XB_ELEMS_PAD (XB_ELEMS + 256)       // 21233920
#define XB_BYTES ((size_t)XB_ELEMS_PAD * 2) // 42467840
#define SLICES 32
#define OUT_ELEMS (B_DIM * N_DIM)           // 512000
#define NSTEP 82                            // 2 channels x 41 BK=32 steps

static __device__ __forceinline__ ushort_t f2bf(float f) {
  unsigned u = __builtin_bit_cast(unsigned, f);
  u += 0x7fffu + ((u >> 16) & 1u);
  return (ushort_t)(u >> 16);
}

// ---------------- x (fp32) -> Xb (bf16) with zeroed pad tail ----------------
__global__ void klindt_cvt_kernel(const float4* __restrict__ x,
                                  unsigned long long* __restrict__ xb) {
  int idx = blockIdx.x * 256 + threadIdx.x;
  if (idx >= XB_ELEMS_PAD / 4) return;
  unsigned long long r = 0ull;
  if (idx < XB_ELEMS / 4) {
    float4 v = x[idx];
    r = (unsigned long long)f2bf(v.x) | ((unsigned long long)f2bf(v.y) << 16) |
        ((unsigned long long)f2bf(v.z) << 32) |
        ((unsigned long long)f2bf(v.w) << 48);
  }
  xb[idx] = r;
}

// ---------------- main GEMM: partials[slice][b][n] ----------------
// FINAL (empirical optimum over 12 rounds = R6 config):
// BM=256 (full M, mw read exactly once), BN=128, BK=32. 512 threads = 8 waves
// (4Mx2N), wave tile 64x64 = acc[4][4] of 16x16x32 bf16 MFMAs.
// XCD-pinned slices (H9): all 16 n-tile blocks of one K-slice land on the
// same XCD (wgid%8 heuristic) so xb re-reads hit that XCD's 4MB L2.
// T4 counted vmcnt(8): barrier drains exactly the 4 A global_load_lds; the
// 8 B-prefetch loads (mw HBM stream) always stay in flight across barriers.
__global__ void __launch_bounds__(512, 4) klindt_gemm_kernel(
    const char* __restrict__ xbb, const char* __restrict__ mwb,
    const float* __restrict__ rw, float* __restrict__ partials) {
  __shared__ ushort_t sA[2][8192];  // [256 m][32 k] bf16, 64B rows, XOR-swz
  __shared__ ushort_t sB[2][4096];  // [128 n][32 k] bf16, 64B rows, XOR-swz

  const int tid = threadIdx.x;
  const int lane = tid & 63;
  const int wid = tid >> 6;
  const int wm = wid >> 1;
  const int wn = wid & 1;
  const int bid = blockIdx.x;
  const int slice = (bid & 7) + 8 * ((bid >> 3) & 3);  // 0..31, XCD-pinned
  const int n0 = (bid >> 5) * 128;                     // 16 n-tiles
  const int c0 = slice * 2;

  f32x4 acc[4][4];
#pragma unroll
  for (int i = 0; i < 4; ++i)
#pragma unroll
    for (int j = 0; j < 4; ++j) {
      acc[i][j][0] = 0.f; acc[i][j][1] = 0.f;
      acc[i][j][2] = 0.f; acc[i][j][3] = 0.f;
    }

  // ---- A staging: linear LDS dest, inverse-swizzled global src (rule #21) --
  uint_t a_gbase[2]; int a_doff[2];
#pragma unroll
  for (int it = 0; it < 2; ++it) {
    int chunk = it * 512 + tid;
    int row = chunk >> 2, t4 = chunk & 3;
    int ss = t4 ^ ((row >> 1) & 3);
    a_gbase[it] = (uint_t)(row * K_DIM + ss * 8) * 2u;  // byte off into xb
    a_doff[it] = chunk * 8;                             // elem off into sA
  }
  // ---- B staging constants (addresses clamped; OOB-n zeroed via rv=0) ----
  uint_t b_goff[2]; int b_eoff[2], b_kj[2];
  float rvl[2], rvh[2];
#pragma unroll
  for (int it = 0; it < 2; ++it) {
    int idx = it * 512 + tid;
    int nl = idx & 15, kq = (idx >> 4) & 7, nh = idx >> 7;
    int n = nh * 16 + nl;
    int ng = n0 + n;
    int ngc = ng < (N_DIM - 1) ? ng : (N_DIM - 1);  // clamp addr
    bool okn = ng < N_DIM;
    b_kj[it] = kq * 4;
    b_goff[it] = (uint_t)kq * 2048000u + (uint_t)ngc * 4u;  // byte off into mw
    int slotp = (kq >> 1) ^ ((nl >> 1) & 3);
    b_eoff[it] = n * 32 + slotp * 8 + (kq & 1) * 4;         // elem off into sB
    rvl[it] = okn ? rw[c0 * N_DIM + ng] : 0.f;
    rvh[it] = okn ? rw[(c0 + 1) * N_DIM + ng] : 0.f;
  }

  // ---- fragment read offsets (swizzle-consistent) ----
  const int r15 = lane & 15, g4 = lane >> 4;
  const int swz = g4 ^ ((r15 >> 1) & 3);
  const int aoffbase = (wm * 64 + r15) * 32 + swz * 8;
  const int boffbase = (wn * 64 + r15) * 32 + swz * 8;

  float mvE[2][4], mvO[2][4];  // B register double-buffer (static parity)

  auto issueA = [&](int buf, int t) {
    int half = (t >= 41) ? 1 : 0;
    int sp = t - 41 * half;
    uint_t kb = ((uint_t)(c0 + half) * (uint_t)P_DIM + (uint_t)sp * 32u) * 2u;
#pragma unroll
    for (int it = 0; it < 2; ++it) {
      const char* g = xbb + (a_gbase[it] + kb);
      __builtin_amdgcn_global_load_lds(
          (const __attribute__((address_space(1))) unsigned int*)g,
          (__attribute__((address_space(3))) unsigned int*)(&sA[buf][a_doff[it]]),
          16, 0, 0);
    }
  };
  auto computeStep = [&](int buf) {
    bf16x8 bfr[4];
#pragma unroll
    for (int fn = 0; fn < 4; ++fn)
      bfr[fn] = *(const bf16x8*)(&sB[buf][boffbase + fn * 512]);
    __builtin_amdgcn_s_setprio(1);
#pragma unroll
    for (int fm = 0; fm < 4; ++fm) {
      bf16x8 afr = *(const bf16x8*)(&sA[buf][aoffbase + fm * 512]);
#pragma unroll
      for (int fn = 0; fn < 4; ++fn)
        acc[fm][fn] = __builtin_amdgcn_mfma_f32_16x16x32_bf16(
            afr, bfr[fn], acc[fm][fn], 0, 0, 0);
    }
    __builtin_amdgcn_s_setprio(0);
  };

#define ISSUE_B(MV, T)                                                        \
  do {                                                                        \
    int half_ = ((T) >= 41) ? 1 : 0;                                          \
    int sp_ = (T)-41 * half_;                                                 \
    uint_t ub_ = (uint_t)sp_ * 16384000u + (uint_t)(c0 + half_) * 8000u;      \
    if (sp_ < 40) { /* uniform: all p in range, no per-elem select */         \
      _Pragma("unroll") for (int it_ = 0; it_ < 2; ++it_) {                   \
        const char* bp_ = mwb + (ub_ + b_goff[it_]);                          \
        _Pragma("unroll") for (int j_ = 0; j_ < 4; ++j_)                      \
          MV[it_][j_] = *(const float*)(bp_ + (uint_t)j_ * 512000u);          \
      }                                                                       \
    } else { /* sp==40: only first 16 k valid */                              \
      _Pragma("unroll") for (int it_ = 0; it_ < 2; ++it_) {                   \
        const char* bp_ = mwb + (ub_ + b_goff[it_]);                          \
        _Pragma("unroll") for (int j_ = 0; j_ < 4; ++j_) {                    \
          bool ok_ = (b_kj[it_] + j_) < 16;                                   \
          MV[it_][j_] = ok_ ? *(const float*)(bp_ + (uint_t)j_ * 512000u)     \
                            : 0.f;                                            \
        }                                                                     \
      }                                                                       \
    }                                                                         \
  } while (0)

#define WRITE_B(BUF, MV, T)                                                   \
  do {                                                                        \
    bool hi_ = ((T) >= 41);                                                   \
    _Pragma("unroll") for (int it_ = 0; it_ < 2; ++it_) {                     \
      float r_ = hi_ ? rvh[it_] : rvl[it_];                                   \
      unsigned long long pk_ = 0ull;                                          \
      _Pragma("unroll") for (int j_ = 0; j_ < 4; ++j_)                        \
        pk_ |= (unsigned long long)f2bf(MV[it_][j_] * r_) << (16 * j_);       \
      *(unsigned long long*)(&sB[BUF][b_eoff[it_]]) = pk_;                    \
    }                                                                         \
  } while (0)

  // ---- prologue ----
  ISSUE_B(mvE, 0);
  issueA(0, 0);
  WRITE_B(0, mvE, 0);  // implicit wait drains B(0); A(0) stays in flight
  ISSUE_B(mvO, 1);
  asm volatile("s_waitcnt vmcnt(8) lgkmcnt(0)" ::: "memory");
  __builtin_amdgcn_sched_barrier(0);
  __builtin_amdgcn_s_barrier();
  __builtin_amdgcn_sched_barrier(0);

#define BODY(S, MV_ISSUE, MV_WRITE)                                           \
  {                                                                           \
    issueA(((S) + 1) & 1, (S) + 1);                                           \
    ISSUE_B(MV_ISSUE, (S) + 2);                                               \
    computeStep((S)&1);                                                       \
    WRITE_B(((S) + 1) & 1, MV_WRITE, (S) + 1);                                \
    asm volatile("s_waitcnt vmcnt(8) lgkmcnt(0)" ::: "memory");               \
    __builtin_amdgcn_sched_barrier(0);                                        \
    __builtin_amdgcn_s_barrier();                                             \
    __builtin_amdgcn_sched_barrier(0);                                        \
  }

  // ---- main loop: steps 0..79 ----
  for (int s = 0; s < 80; s += 2) {
    BODY(s, mvE, mvO);
    BODY(s + 1, mvO, mvE);
  }
  // ---- peel s=80 (no B prefetch; full drain so A(81) is guaranteed) ----
  issueA(1, 81);
  computeStep(0);
  WRITE_B(1, mvO, 81);
  asm volatile("s_waitcnt vmcnt(0) lgkmcnt(0)" ::: "memory");
  __builtin_amdgcn_sched_barrier(0);
  __builtin_amdgcn_s_barrier();
  __builtin_amdgcn_sched_barrier(0);
  // ---- s=81 ----
  computeStep(1);

  // ---- epilogue: fp32 partials for this K-slice ----
  float* pb = partials + (size_t)slice * OUT_ELEMS;
#pragma unroll
  for (int fm = 0; fm < 4; ++fm) {
#pragma unroll
    for (int fn = 0; fn < 4; ++fn) {
      int nn = n0 + wn * 64 + fn * 16 + r15;
      if (nn < N_DIM) {
#pragma unroll
        for (int rr = 0; rr < 4; ++rr) {
          int m = wm * 64 + fm * 16 + g4 * 4 + rr;
          pb[m * N_DIM + nn] = acc[fm][fn][rr];
        }
      }
    }
  }
#undef BODY
#undef ISSUE_B
#undef WRITE_B
}

// ---------------- deterministic split-K reduction ----------------
__global__ void klindt_reduce_kernel(const float* __restrict__ part,
                                     float* __restrict__ out) {
  int i = blockIdx.x * 256 + threadIdx.x;
  if (i < OUT_ELEMS) {
    float s = 0.f;
#pragma unroll
    for (int k = 0; k < SLICES; ++k) s += part[(size_t)k * OUT_ELEMS + i];
    out[i] = s;
  }
}

extern "C" void kernel_launch(void* const* d_in, const int* in_sizes, int n_in,
                              void* d_out, int out_size, void* d_ws,
                              size_t ws_size, hipStream_t stream) {
  (void)in_sizes; (void)n_in; (void)out_size; (void)ws_size;
  const float* x = (const float*)d_in[0];
  const char* mwb = (const char*)d_in[1];
  const float* rw = (const float*)d_in[2];
  float* out = (float*)d_out;

  char* xbb = (char*)d_ws;
  float* partials = (float*)((char*)d_ws + XB_BYTES);

  {
    int nvec = XB_ELEMS_PAD / 4;
    int grid = (nvec + 255) / 256;
    klindt_cvt_kernel<<<grid, 256, 0, stream>>>((const float4*)x,
                                                (unsigned long long*)xbb);
  }
  {
    klindt_gemm_kernel<<<512, 512, 0, stream>>>(xbb, mwb, rw, partials);
  }
  {
    int grid = (OUT_ELEMS + 255) / 256;
    klindt_reduce_kernel<<<grid, 256, 0, stream>>>(partials, out);
  }
}